// Round 10
// baseline (812.193 us; speedup 1.0000x reference)
//
#include <hip/hip_runtime.h>
#include <hip/hip_fp16.h>
#include <math.h>

#define N_NODES 50000
#define E_EDGES 800000
#define E_TOT   850000   // E + N self loops
#define HC 128
#define NHEAD 4
#define LIN 256
#define OUTC 10
#define NG 64
#define NEG_SLOPE 0.2f

__device__ __forceinline__ float lrelu(float v) { return v > 0.f ? v : NEG_SLOPE * v; }

// ---------------------------------------------------------------------------
// GEMM + attention logits: h = x@W (N x128 @ 128x128); alpha_{src,dst}[n,h].
// 4 rows x 16 cols per thread; cols interleaved (c = t*4 + 32u). h emitted in
// FP16 (only consumer is the gather). All arithmetic fp32.
// ---------------------------------------------------------------------------
__global__ __launch_bounds__(256, 2) void k_gemm_alpha(
    const float* __restrict__ x, const float* __restrict__ W,
    const float* __restrict__ a_s, const float* __restrict__ a_d,
    __half* __restrict__ h, float* __restrict__ asrc, float* __restrict__ adst) {
  __shared__ float Ws[HC * HC];  // 64 KB
  int tid = threadIdx.x;
  {
    const float4* Wg = (const float4*)W;
    float4* Wv = (float4*)Ws;
#pragma unroll
    for (int i = 0; i < 16; i++) Wv[tid + i * 256] = Wg[tid + i * 256];
  }
  __syncthreads();
  int rl = tid >> 3, t = tid & 7;
  int base = blockIdx.x * 128;
  int row[4];
  const float4* xr[4];
#pragma unroll
  for (int r = 0; r < 4; r++) {
    row[r] = base + rl + 32 * r;
    int rc = row[r] < N_NODES ? row[r] : N_NODES - 1;  // clamp, store-guarded
    xr[r] = (const float4*)(x + (size_t)rc * HC);
  }
  float acc[4][16];
#pragma unroll
  for (int r = 0; r < 4; r++)
#pragma unroll
    for (int j = 0; j < 16; j++) acc[r][j] = 0.f;

  for (int k4 = 0; k4 < 32; k4++) {
    float4 xa = xr[0][k4], xb = xr[1][k4], xc = xr[2][k4], xd = xr[3][k4];
#pragma unroll
    for (int kk = 0; kk < 4; kk++) {
      const float* wb = Ws + (k4 * 4 + kk) * HC + t * 4;
      float4 w0 = *(const float4*)(wb);
      float4 w1 = *(const float4*)(wb + 32);
      float4 w2 = *(const float4*)(wb + 64);
      float4 w3 = *(const float4*)(wb + 96);
      float xs[4];
      xs[0] = (kk == 0) ? xa.x : (kk == 1) ? xa.y : (kk == 2) ? xa.z : xa.w;
      xs[1] = (kk == 0) ? xb.x : (kk == 1) ? xb.y : (kk == 2) ? xb.z : xb.w;
      xs[2] = (kk == 0) ? xc.x : (kk == 1) ? xc.y : (kk == 2) ? xc.z : xc.w;
      xs[3] = (kk == 0) ? xd.x : (kk == 1) ? xd.y : (kk == 2) ? xd.z : xd.w;
#pragma unroll
      for (int r = 0; r < 4; r++) {
        float xv = xs[r];
        acc[r][0] += xv * w0.x;  acc[r][1] += xv * w0.y;
        acc[r][2] += xv * w0.z;  acc[r][3] += xv * w0.w;
        acc[r][4] += xv * w1.x;  acc[r][5] += xv * w1.y;
        acc[r][6] += xv * w1.z;  acc[r][7] += xv * w1.w;
        acc[r][8] += xv * w2.x;  acc[r][9] += xv * w2.y;
        acc[r][10] += xv * w2.z; acc[r][11] += xv * w2.w;
        acc[r][12] += xv * w3.x; acc[r][13] += xv * w3.y;
        acc[r][14] += xv * w3.z; acc[r][15] += xv * w3.w;
      }
    }
  }

#pragma unroll
  for (int r = 0; r < 4; r++) {
    // col c = t*4 + 32u + j  ->  head = u, channel = t*4 + j
    float ps[4], pd[4];
#pragma unroll
    for (int u = 0; u < 4; u++) {
      float s = 0.f, d = 0.f;
#pragma unroll
      for (int j = 0; j < 4; j++) {
        float av = acc[r][u * 4 + j];
        s += av * a_s[u * 32 + t * 4 + j];
        d += av * a_d[u * 32 + t * 4 + j];
      }
      s += __shfl_xor(s, 1); s += __shfl_xor(s, 2); s += __shfl_xor(s, 4);
      d += __shfl_xor(d, 1); d += __shfl_xor(d, 2); d += __shfl_xor(d, 4);
      ps[u] = s; pd[u] = d;
    }
    if (row[r] < N_NODES) {
      __half* hr = h + (size_t)row[r] * HC;
#pragma unroll
      for (int u = 0; u < 4; u++) {
        __half2* hp2 = (__half2*)(hr + t * 4 + 32 * u);
        hp2[0] = __floats2half2_rn(acc[r][u * 4 + 0], acc[r][u * 4 + 1]);
        hp2[1] = __floats2half2_rn(acc[r][u * 4 + 2], acc[r][u * 4 + 3]);
      }
      if (t < 4) {
        float vs = (t == 0) ? ps[0] : (t == 1) ? ps[1] : (t == 2) ? ps[2] : ps[3];
        float vd = (t == 0) ? pd[0] : (t == 1) ? pd[1] : (t == 2) ? pd[2] : pd[3];
        asrc[row[r] * NHEAD + t] = vs;
        adst[row[r] * NHEAD + t] = vd;
      }
    }
  }
}

// ---------------------------------------------------------------------------
// CSR build: histogram -> exclusive scan -> scatter (int atomics only)
// ---------------------------------------------------------------------------
__global__ __launch_bounds__(256) void k_hist(
    const int* __restrict__ dst, int* __restrict__ deg) {
  int e = blockIdx.x * 256 + threadIdx.x;
  if (e >= E_TOT) return;
  int d = (e < E_EDGES) ? dst[e] : e - E_EDGES;
  atomicAdd(&deg[d], 1);
}

__global__ __launch_bounds__(1024) void k_scan(
    const int* __restrict__ deg, int* __restrict__ row_off,
    unsigned* __restrict__ pooled) {
  // fold the pooled zeroing in here (saves one dispatch)
  if (threadIdx.x < NG * HC / 8) {
    ((uint2*)pooled)[threadIdx.x * 4 + 0] = make_uint2(0u, 0u);
    ((uint2*)pooled)[threadIdx.x * 4 + 1] = make_uint2(0u, 0u);
    ((uint2*)pooled)[threadIdx.x * 4 + 2] = make_uint2(0u, 0u);
    ((uint2*)pooled)[threadIdx.x * 4 + 3] = make_uint2(0u, 0u);
  }
  __shared__ int ps[1024];
  int tid = threadIdx.x;
  const int CH = (N_NODES + 1023) / 1024;  // 49
  int base = tid * CH;
  int sum = 0;
  for (int i = 0; i < CH; i++) {
    int idx = base + i;
    if (idx < N_NODES) sum += deg[idx];
  }
  ps[tid] = sum;
  __syncthreads();
  for (int off = 1; off < 1024; off <<= 1) {
    int v = (tid >= off) ? ps[tid - off] : 0;
    __syncthreads();
    ps[tid] += v;
    __syncthreads();
  }
  int run = (tid ? ps[tid - 1] : 0);
  for (int i = 0; i < CH; i++) {
    int idx = base + i;
    if (idx < N_NODES) { row_off[idx] = run; run += deg[idx]; }
  }
  if (tid == 1023) row_off[N_NODES] = run;
}

__global__ __launch_bounds__(256) void k_scatter(
    const int* __restrict__ src, const int* __restrict__ dst,
    const int* __restrict__ row_off, int* __restrict__ cnt,
    int* __restrict__ csr_src) {
  int e = blockIdx.x * 256 + threadIdx.x;
  if (e >= E_TOT) return;
  int s, d;
  if (e < E_EDGES) { s = src[e]; d = dst[e]; } else { s = d = e - E_EDGES; }
  int pos = row_off[d] + atomicAdd(&cnt[d], 1);
  csr_src[pos] = s;
}

// 32-lane butterflies (stay within a half-wave)
#define BFLY32_MAX4(m0, m1, m2, m3)                        \
  _Pragma("unroll") for (int off = 1; off < 32; off <<= 1) { \
    m0 = fmaxf(m0, __shfl_xor(m0, off));                   \
    m1 = fmaxf(m1, __shfl_xor(m1, off));                   \
    m2 = fmaxf(m2, __shfl_xor(m2, off));                   \
    m3 = fmaxf(m3, __shfl_xor(m3, off));                   \
  }
#define BFLY32_SUM4(s0, s1, s2, s3)                        \
  _Pragma("unroll") for (int off = 1; off < 32; off <<= 1) { \
    s0 += __shfl_xor(s0, off);                             \
    s1 += __shfl_xor(s1, off);                             \
    s2 += __shfl_xor(s2, off);                             \
    s3 += __shfl_xor(s3, off);                             \
  }

// ---------------------------------------------------------------------------
// Fused softmax + aggregation. TWO nodes per wave: each half-wave (32 lanes)
// fully owns one node; lane owns 4 fp16 feats (8B dwordx2 — proven width).
// One gather instruction covers 2 edges (one per half) -> gather-instr count
// per edge halved vs R9. No cross-half combines, no guarded epilogue.
// Stage 1 per half: 2 edge slots/lane, stats via 32-lane butterflies,
// weights to LDS. Stage 2: unroll x4 over wave-uniform max degree with
// clamped index + zero weight for the shorter half.
// ---------------------------------------------------------------------------
__global__ __launch_bounds__(256) void k_aggr(
    const int* __restrict__ row_off, const int* __restrict__ csr_src,
    const float* __restrict__ asrc, const float* __restrict__ adst,
    const __half* __restrict__ h, const float* __restrict__ bias,
    const int* __restrict__ batch, float* __restrict__ out_h,
    unsigned* __restrict__ pooled, int do_pool) {
  __shared__ int    sv_lds[8][68];   // padded: ns stride 68 (%32=4) kills aliasing
  __shared__ float4 w_lds[8][66];    // padded: ns stride 66*4 words (%32=8)
  int hl = threadIdx.x & 31;         // lane within half-wave
  int ns = threadIdx.x >> 5;         // half-wave slot in block (0..7)
  int node = blockIdx.x * 8 + ns;
  if (node >= N_NODES) return;
  int head = hl >> 3;                // feats hl*4..hl*4+3 -> head = hl*4/32
  int lo = row_off[node], hi = row_off[node + 1];
  int deg = hi - lo;
  int od = __shfl_xor(deg, 32);      // other half's degree (whole wave active here)
  float4 ad4 = ((const float4*)adst)[node];  // broadcast within half
  float4 acc = make_float4(0.f, 0.f, 0.f, 0.f);
  float rden;

  if (deg <= 64) {
    // --- stage 1: stats + weights; 2 edge slots per lane (hl, hl+32) ---
    bool v0 = hl < deg, v1 = hl + 32 < deg;
    int sv0 = v0 ? csr_src[lo + hl] : 0;
    int sv1 = v1 ? csr_src[lo + hl + 32] : 0;
    float4 a0 = ((const float4*)asrc)[sv0];
    float4 a1 = ((const float4*)asrc)[sv1];
    float e00 = v0 ? lrelu(a0.x + ad4.x) : -1e30f;
    float e01 = v0 ? lrelu(a0.y + ad4.y) : -1e30f;
    float e02 = v0 ? lrelu(a0.z + ad4.z) : -1e30f;
    float e03 = v0 ? lrelu(a0.w + ad4.w) : -1e30f;
    float e10 = v1 ? lrelu(a1.x + ad4.x) : -1e30f;
    float e11 = v1 ? lrelu(a1.y + ad4.y) : -1e30f;
    float e12 = v1 ? lrelu(a1.z + ad4.z) : -1e30f;
    float e13 = v1 ? lrelu(a1.w + ad4.w) : -1e30f;
    float m0 = fmaxf(e00, e10), m1 = fmaxf(e01, e11);
    float m2 = fmaxf(e02, e12), m3 = fmaxf(e03, e13);
    BFLY32_MAX4(m0, m1, m2, m3)
    float w00 = expf(e00 - m0), w01 = expf(e01 - m1);
    float w02 = expf(e02 - m2), w03 = expf(e03 - m3);
    float w10 = expf(e10 - m0), w11 = expf(e11 - m1);
    float w12 = expf(e12 - m2), w13 = expf(e13 - m3);  // invalid -> exp(-big)=0
    float s0 = w00 + w10, s1 = w01 + w11, s2 = w02 + w12, s3 = w03 + w13;
    BFLY32_SUM4(s0, s1, s2, s3)
    sv_lds[ns][hl] = sv0;
    sv_lds[ns][hl + 32] = sv1;
    w_lds[ns][hl] = make_float4(w00, w01, w02, w03);
    w_lds[ns][hl + 32] = make_float4(w10, w11, w12, w13);
    float S = (head == 0) ? s0 : (head == 1) ? s1 : (head == 2) ? s2 : s3;
    rden = 1.f / S;

    // --- stage 2: gather loop over wave-uniform max degree ---
    int degm = (od <= 64) ? max(deg, od) : deg;
    const int* svp = sv_lds[ns];
    const float* wp = (const float*)&w_lds[ns][0];
    const __half* hb = h;
    int fo = hl * 4;
#define AGG_BODY(JJ)                                                   \
    {                                                                  \
      int jc = min((JJ), deg - 1);                                     \
      int idx = svp[jc];                                               \
      float w = ((JJ) < deg) ? wp[jc * 4 + head] : 0.f;                \
      float2 raw = *(const float2*)(hb + (size_t)idx * HC + fo);       \
      __half2 p0 = *(__half2*)&raw.x;                                  \
      __half2 p1 = *(__half2*)&raw.y;                                  \
      float2 f0 = __half22float2(p0);                                  \
      float2 f1 = __half22float2(p1);                                  \
      acc.x = fmaf(w, f0.x, acc.x); acc.y = fmaf(w, f0.y, acc.y);      \
      acc.z = fmaf(w, f1.x, acc.z); acc.w = fmaf(w, f1.y, acc.w);      \
    }
    int j = 0;
    for (; j + 4 <= degm; j += 4) {
      AGG_BODY(j + 0)
      AGG_BODY(j + 1)
      AGG_BODY(j + 2)
      AGG_BODY(j + 3)
    }
    for (; j < degm; j++) AGG_BODY(j)
#undef AGG_BODY
  } else {
    // --- rare generic path (deg > 64): per-half, strided online stats ---
    float m[4] = {-1e30f, -1e30f, -1e30f, -1e30f};
    float s[4] = {0.f, 0.f, 0.f, 0.f};
    for (int e = hl; e < deg; e += 32) {
      int sv = csr_src[lo + e];
      float4 a = ((const float4*)asrc)[sv];
      float t[4];
      t[0] = lrelu(a.x + ad4.x); t[1] = lrelu(a.y + ad4.y);
      t[2] = lrelu(a.z + ad4.z); t[3] = lrelu(a.w + ad4.w);
#pragma unroll
      for (int q = 0; q < 4; q++) {
        if (t[q] > m[q]) {
          s[q] = s[q] * expf(m[q] - t[q]) + 1.f;
          m[q] = t[q];
        } else {
          s[q] += expf(t[q] - m[q]);
        }
      }
    }
#pragma unroll
    for (int off = 1; off < 32; off <<= 1) {
#pragma unroll
      for (int q = 0; q < 4; q++) {
        float mo = __shfl_xor(m[q], off);
        float so = __shfl_xor(s[q], off);
        float mn = fmaxf(m[q], mo);
        s[q] = s[q] * expf(m[q] - mn) + so * expf(mo - mn);
        m[q] = mn;
      }
    }
    float mh = m[head];
    float adh = (head == 0) ? ad4.x : (head == 1) ? ad4.y : (head == 2) ? ad4.z : ad4.w;
    rden = 1.f / s[head];
    int fo = hl * 4;
    for (int jj = 0; jj < deg; jj++) {
      int idx = csr_src[lo + jj];  // broadcast within half
      float av = asrc[idx * NHEAD + head];
      float w = expf(lrelu(av + adh) - mh);
      float2 raw = *(const float2*)(h + (size_t)idx * HC + fo);
      __half2 p0 = *(__half2*)&raw.x;
      __half2 p1 = *(__half2*)&raw.y;
      float2 f0 = __half22float2(p0);
      float2 f1 = __half22float2(p1);
      acc.x = fmaf(w, f0.x, acc.x); acc.y = fmaf(w, f0.y, acc.y);
      acc.z = fmaf(w, f1.x, acc.z); acc.w = fmaf(w, f1.y, acc.w);
    }
  }

  // --- epilogue: normalize + bias + relu + store + (final) max-pool ---
  float4 b4 = *(const float4*)(bias + hl * 4);
  float vx = fmaxf(acc.x * rden + b4.x, 0.f);
  float vy = fmaxf(acc.y * rden + b4.y, 0.f);
  float vz = fmaxf(acc.z * rden + b4.z, 0.f);
  float vw = fmaxf(acc.w * rden + b4.w, 0.f);
  *(float4*)(out_h + (size_t)node * HC + hl * 4) = make_float4(vx, vy, vz, vw);
  if (do_pool) {
    int g = batch[node];
    unsigned* pp = pooled + g * HC + hl * 4;
    // post-relu values >= 0: bit compare == float compare; init 0 matches the
    // reference's where(isfinite, pooled, 0) empty-graph guard.
    atomicMax(pp + 0, __float_as_uint(vx));
    atomicMax(pp + 1, __float_as_uint(vy));
    atomicMax(pp + 2, __float_as_uint(vz));
    atomicMax(pp + 3, __float_as_uint(vw));
  }
}

// final head: out[g] = (pooled[g] @ Wlin + blin) @ Wout + bout ; 1 block/graph
__global__ __launch_bounds__(256) void k_mlp(
    const float* __restrict__ pooled, const float* __restrict__ Wlin,
    const float* __restrict__ blin, const float* __restrict__ Wout,
    const float* __restrict__ bout, float* __restrict__ out) {
  __shared__ float p[HC];
  __shared__ float z[LIN];
  int g = blockIdx.x, tid = threadIdx.x;
  if (tid < HC) p[tid] = pooled[g * HC + tid];
  __syncthreads();
  float zv = blin[tid];
  for (int k = 0; k < HC; k++) zv += p[k] * Wlin[k * LIN + tid];
  z[tid] = zv;
  __syncthreads();
  if (tid < OUTC) {
    float o = bout[tid];
    for (int k = 0; k < LIN; k++) o += z[k] * Wout[k * OUTC + tid];
    out[g * OUTC + tid] = o;
  }
}

extern "C" void kernel_launch(void* const* d_in, const int* in_sizes, int n_in,
                              void* d_out, int out_size, void* d_ws, size_t ws_size,
                              hipStream_t stream) {
  const float* x     = (const float*)d_in[0];
  const int*   ei    = (const int*)d_in[1];
  const int*   batch = (const int*)d_in[2];
  const float* Wl[3] = {(const float*)d_in[3], (const float*)d_in[7], (const float*)d_in[11]};
  const float* As[3] = {(const float*)d_in[4], (const float*)d_in[8], (const float*)d_in[12]};
  const float* Ad[3] = {(const float*)d_in[5], (const float*)d_in[9], (const float*)d_in[13]};
  const float* Bi[3] = {(const float*)d_in[6], (const float*)d_in[10], (const float*)d_in[14]};
  const float* Wlin  = (const float*)d_in[15];
  const float* blin  = (const float*)d_in[16];
  const float* Wout  = (const float*)d_in[17];
  const float* bout  = (const float*)d_in[18];
  float* out = (float*)d_out;

  // workspace layout (float offsets); h is fp16 (N*128 halves = 3.2M floats)
  float* ws = (float*)d_ws;
  __half*   h       = (__half*)ws;                 // N*128 halves
  float*    nodeB   = ws + 6400000;                // N*128 fp32
  float*    asrc    = ws + 12800000;               // N*4
  float*    adst    = ws + 13000000;               // N*4
  int*      deg     = (int*)(ws + 13200000);       // N
  int*      cnt     = (int*)(ws + 13250000);       // N (adjacent to deg)
  int*      row_off = (int*)(ws + 13300000);       // N+1
  int*      csr_src = (int*)(ws + 13350008);       // E_TOT
  unsigned* pooled  = (unsigned*)(ws + 14200008);  // 64*128

  const int* srcp = ei;
  const int* dstp = ei + E_EDGES;

  hipMemsetAsync(deg, 0, 2 * N_NODES * sizeof(int), stream);

  // CSR by dst — built once, reused by all 3 layers
  k_hist<<<(E_TOT + 255) / 256, 256, 0, stream>>>(dstp, deg);
  k_scan<<<1, 1024, 0, stream>>>(deg, row_off, pooled);
  k_scatter<<<(E_TOT + 255) / 256, 256, 0, stream>>>(srcp, dstp, row_off, cnt, csr_src);

  const float* lin_in = x;
  for (int L = 0; L < 3; L++) {
    k_gemm_alpha<<<(N_NODES + 127) / 128, 256, 0, stream>>>(
        lin_in, Wl[L], As[L], Ad[L], h, asrc, adst);
    k_aggr<<<(N_NODES + 7) / 8, 256, 0, stream>>>(
        row_off, csr_src, asrc, adst, h, Bi[L], batch,
        nodeB, pooled, (L == 2) ? 1 : 0);
    lin_in = nodeB;
  }
  k_mlp<<<NG, 256, 0, stream>>>((const float*)pooled, Wlin, blin, Wout, bout, out);
}

// Round 11
// 617.788 us; speedup vs baseline: 1.3147x; 1.3147x over previous
//
#include <hip/hip_runtime.h>
#include <hip/hip_fp16.h>
#include <math.h>

#define N_NODES 50000
#define E_EDGES 800000
#define E_TOT   850000   // E + N self loops
#define HC 128
#define NHEAD 4
#define LIN 256
#define OUTC 10
#define NG 64
#define NEG_SLOPE 0.2f

__device__ __forceinline__ float lrelu(float v) { return v > 0.f ? v : NEG_SLOPE * v; }

// ---------------------------------------------------------------------------
// GEMM + attention logits: h = x@W (N x128 @ 128x128); alpha_{src,dst}[n,h].
// 4 rows x 16 cols per thread; cols interleaved (c = t*4 + 32u). h emitted in
// FP16 (only consumer is the gather). All arithmetic fp32.
// ---------------------------------------------------------------------------
__global__ __launch_bounds__(256, 2) void k_gemm_alpha(
    const float* __restrict__ x, const float* __restrict__ W,
    const float* __restrict__ a_s, const float* __restrict__ a_d,
    __half* __restrict__ h, float* __restrict__ asrc, float* __restrict__ adst) {
  __shared__ float Ws[HC * HC];  // 64 KB
  int tid = threadIdx.x;
  {
    const float4* Wg = (const float4*)W;
    float4* Wv = (float4*)Ws;
#pragma unroll
    for (int i = 0; i < 16; i++) Wv[tid + i * 256] = Wg[tid + i * 256];
  }
  __syncthreads();
  int rl = tid >> 3, t = tid & 7;
  int base = blockIdx.x * 128;
  int row[4];
  const float4* xr[4];
#pragma unroll
  for (int r = 0; r < 4; r++) {
    row[r] = base + rl + 32 * r;
    int rc = row[r] < N_NODES ? row[r] : N_NODES - 1;  // clamp, store-guarded
    xr[r] = (const float4*)(x + (size_t)rc * HC);
  }
  float acc[4][16];
#pragma unroll
  for (int r = 0; r < 4; r++)
#pragma unroll
    for (int j = 0; j < 16; j++) acc[r][j] = 0.f;

  for (int k4 = 0; k4 < 32; k4++) {
    float4 xa = xr[0][k4], xb = xr[1][k4], xc = xr[2][k4], xd = xr[3][k4];
#pragma unroll
    for (int kk = 0; kk < 4; kk++) {
      const float* wb = Ws + (k4 * 4 + kk) * HC + t * 4;
      float4 w0 = *(const float4*)(wb);
      float4 w1 = *(const float4*)(wb + 32);
      float4 w2 = *(const float4*)(wb + 64);
      float4 w3 = *(const float4*)(wb + 96);
      float xs[4];
      xs[0] = (kk == 0) ? xa.x : (kk == 1) ? xa.y : (kk == 2) ? xa.z : xa.w;
      xs[1] = (kk == 0) ? xb.x : (kk == 1) ? xb.y : (kk == 2) ? xb.z : xb.w;
      xs[2] = (kk == 0) ? xc.x : (kk == 1) ? xc.y : (kk == 2) ? xc.z : xc.w;
      xs[3] = (kk == 0) ? xd.x : (kk == 1) ? xd.y : (kk == 2) ? xd.z : xd.w;
#pragma unroll
      for (int r = 0; r < 4; r++) {
        float xv = xs[r];
        acc[r][0] += xv * w0.x;  acc[r][1] += xv * w0.y;
        acc[r][2] += xv * w0.z;  acc[r][3] += xv * w0.w;
        acc[r][4] += xv * w1.x;  acc[r][5] += xv * w1.y;
        acc[r][6] += xv * w1.z;  acc[r][7] += xv * w1.w;
        acc[r][8] += xv * w2.x;  acc[r][9] += xv * w2.y;
        acc[r][10] += xv * w2.z; acc[r][11] += xv * w2.w;
        acc[r][12] += xv * w3.x; acc[r][13] += xv * w3.y;
        acc[r][14] += xv * w3.z; acc[r][15] += xv * w3.w;
      }
    }
  }

#pragma unroll
  for (int r = 0; r < 4; r++) {
    // col c = t*4 + 32u + j  ->  head = u, channel = t*4 + j
    float ps[4], pd[4];
#pragma unroll
    for (int u = 0; u < 4; u++) {
      float s = 0.f, d = 0.f;
#pragma unroll
      for (int j = 0; j < 4; j++) {
        float av = acc[r][u * 4 + j];
        s += av * a_s[u * 32 + t * 4 + j];
        d += av * a_d[u * 32 + t * 4 + j];
      }
      s += __shfl_xor(s, 1); s += __shfl_xor(s, 2); s += __shfl_xor(s, 4);
      d += __shfl_xor(d, 1); d += __shfl_xor(d, 2); d += __shfl_xor(d, 4);
      ps[u] = s; pd[u] = d;
    }
    if (row[r] < N_NODES) {
      __half* hr = h + (size_t)row[r] * HC;
#pragma unroll
      for (int u = 0; u < 4; u++) {
        __half2* hp2 = (__half2*)(hr + t * 4 + 32 * u);
        hp2[0] = __floats2half2_rn(acc[r][u * 4 + 0], acc[r][u * 4 + 1]);
        hp2[1] = __floats2half2_rn(acc[r][u * 4 + 2], acc[r][u * 4 + 3]);
      }
      if (t < 4) {
        float vs = (t == 0) ? ps[0] : (t == 1) ? ps[1] : (t == 2) ? ps[2] : ps[3];
        float vd = (t == 0) ? pd[0] : (t == 1) ? pd[1] : (t == 2) ? pd[2] : pd[3];
        asrc[row[r] * NHEAD + t] = vs;
        adst[row[r] * NHEAD + t] = vd;
      }
    }
  }
}

// ---------------------------------------------------------------------------
// CSR build: histogram -> exclusive scan -> scatter (int atomics only)
// ---------------------------------------------------------------------------
__global__ __launch_bounds__(256) void k_hist(
    const int* __restrict__ dst, int* __restrict__ deg) {
  int e = blockIdx.x * 256 + threadIdx.x;
  if (e >= E_TOT) return;
  int d = (e < E_EDGES) ? dst[e] : e - E_EDGES;
  atomicAdd(&deg[d], 1);
}

__global__ __launch_bounds__(1024) void k_scan(
    const int* __restrict__ deg, int* __restrict__ row_off,
    unsigned* __restrict__ pooled) {
  // fold the pooled zeroing in here (saves one dispatch)
  if (threadIdx.x < NG * HC / 8) {
    ((uint2*)pooled)[threadIdx.x * 4 + 0] = make_uint2(0u, 0u);
    ((uint2*)pooled)[threadIdx.x * 4 + 1] = make_uint2(0u, 0u);
    ((uint2*)pooled)[threadIdx.x * 4 + 2] = make_uint2(0u, 0u);
    ((uint2*)pooled)[threadIdx.x * 4 + 3] = make_uint2(0u, 0u);
  }
  __shared__ int ps[1024];
  int tid = threadIdx.x;
  const int CH = (N_NODES + 1023) / 1024;  // 49
  int base = tid * CH;
  int sum = 0;
  for (int i = 0; i < CH; i++) {
    int idx = base + i;
    if (idx < N_NODES) sum += deg[idx];
  }
  ps[tid] = sum;
  __syncthreads();
  for (int off = 1; off < 1024; off <<= 1) {
    int v = (tid >= off) ? ps[tid - off] : 0;
    __syncthreads();
    ps[tid] += v;
    __syncthreads();
  }
  int run = (tid ? ps[tid - 1] : 0);
  for (int i = 0; i < CH; i++) {
    int idx = base + i;
    if (idx < N_NODES) { row_off[idx] = run; run += deg[idx]; }
  }
  if (tid == 1023) row_off[N_NODES] = run;
}

__global__ __launch_bounds__(256) void k_scatter(
    const int* __restrict__ src, const int* __restrict__ dst,
    const int* __restrict__ row_off, int* __restrict__ cnt,
    int* __restrict__ csr_src) {
  int e = blockIdx.x * 256 + threadIdx.x;
  if (e >= E_TOT) return;
  int s, d;
  if (e < E_EDGES) { s = src[e]; d = dst[e]; } else { s = d = e - E_EDGES; }
  int pos = row_off[d] + atomicAdd(&cnt[d], 1);
  csr_src[pos] = s;
}

#define BFLY_MAX4(m0, m1, m2, m3)                         \
  _Pragma("unroll") for (int off = 1; off < 64; off <<= 1) { \
    m0 = fmaxf(m0, __shfl_xor(m0, off));                  \
    m1 = fmaxf(m1, __shfl_xor(m1, off));                  \
    m2 = fmaxf(m2, __shfl_xor(m2, off));                  \
    m3 = fmaxf(m3, __shfl_xor(m3, off));                  \
  }
#define BFLY_SUM4(s0, s1, s2, s3)                         \
  _Pragma("unroll") for (int off = 1; off < 64; off <<= 1) { \
    s0 += __shfl_xor(s0, off);                            \
    s1 += __shfl_xor(s1, off);                            \
    s2 += __shfl_xor(s2, off);                            \
    s3 += __shfl_xor(s3, off);                            \
  }

// ---------------------------------------------------------------------------
// Fused softmax + aggregation — R6 structure with fp16 h (best measured:
// 143 us). One wave per dst node; lane owns 2 feats; head = lane/16.
// LAW (R5/R7/R10): every gather instruction's 64 lanes must cover exactly ONE
// contiguous h-row span — never split the wave's lanes across rows.
// ---------------------------------------------------------------------------
__global__ __launch_bounds__(256) void k_aggr(
    const int* __restrict__ row_off, const int* __restrict__ csr_src,
    const float* __restrict__ asrc, const float* __restrict__ adst,
    const __half* __restrict__ h, const float* __restrict__ bias,
    const int* __restrict__ batch, float* __restrict__ out_h,
    unsigned* __restrict__ pooled, int do_pool) {
  __shared__ int   sv_lds[4][64];
  __shared__ float w_lds[4][64][4];
  int gid = blockIdx.x * 256 + threadIdx.x;
  int node = gid >> 6, lane = gid & 63, wl = threadIdx.x >> 6;
  if (node >= N_NODES) return;
  int head = lane >> 4;
  int lo = row_off[node], hi = row_off[node + 1];
  int deg = hi - lo;
  float4 ad4 = ((const float4*)adst)[node];  // broadcast
  float ax = 0.f, ay = 0.f;
  float S;

  if (deg <= 64) {
    int j = lo + lane;
    int sv = (j < hi) ? csr_src[j] : 0;
    float4 a4 = ((const float4*)asrc)[sv];
    bool valid = (j < hi);
    float e0 = valid ? lrelu(a4.x + ad4.x) : -1e30f;
    float e1 = valid ? lrelu(a4.y + ad4.y) : -1e30f;
    float e2 = valid ? lrelu(a4.z + ad4.z) : -1e30f;
    float e3 = valid ? lrelu(a4.w + ad4.w) : -1e30f;
    float m0 = e0, m1 = e1, m2 = e2, m3 = e3;
    BFLY_MAX4(m0, m1, m2, m3)
    float w0 = expf(e0 - m0), w1 = expf(e1 - m1);
    float w2 = expf(e2 - m2), w3 = expf(e3 - m3);  // invalid lanes -> 0
    float s0 = w0, s1 = w1, s2 = w2, s3 = w3;
    BFLY_SUM4(s0, s1, s2, s3)
    sv_lds[wl][lane] = sv;
    *(float4*)&w_lds[wl][lane][0] = make_float4(w0, w1, w2, w3);
    S = (head == 0) ? s0 : (head == 1) ? s1 : (head == 2) ? s2 : s3;
    int jj = 0;
    for (; jj + 8 <= deg; jj += 8) {
      int i0 = sv_lds[wl][jj + 0], i1 = sv_lds[wl][jj + 1];
      int i2 = sv_lds[wl][jj + 2], i3 = sv_lds[wl][jj + 3];
      int i4 = sv_lds[wl][jj + 4], i5 = sv_lds[wl][jj + 5];
      int i6 = sv_lds[wl][jj + 6], i7 = sv_lds[wl][jj + 7];
      float wA = w_lds[wl][jj + 0][head], wB = w_lds[wl][jj + 1][head];
      float wC = w_lds[wl][jj + 2][head], wD = w_lds[wl][jj + 3][head];
      float wE = w_lds[wl][jj + 4][head], wF = w_lds[wl][jj + 5][head];
      float wG = w_lds[wl][jj + 6][head], wH = w_lds[wl][jj + 7][head];
      float2 h0 = __half22float2(*(const __half2*)(h + (size_t)i0 * HC + lane * 2));
      float2 h1 = __half22float2(*(const __half2*)(h + (size_t)i1 * HC + lane * 2));
      float2 h2 = __half22float2(*(const __half2*)(h + (size_t)i2 * HC + lane * 2));
      float2 h3 = __half22float2(*(const __half2*)(h + (size_t)i3 * HC + lane * 2));
      float2 h4 = __half22float2(*(const __half2*)(h + (size_t)i4 * HC + lane * 2));
      float2 h5 = __half22float2(*(const __half2*)(h + (size_t)i5 * HC + lane * 2));
      float2 h6 = __half22float2(*(const __half2*)(h + (size_t)i6 * HC + lane * 2));
      float2 h7 = __half22float2(*(const __half2*)(h + (size_t)i7 * HC + lane * 2));
      ax += wA * h0.x; ay += wA * h0.y;
      ax += wB * h1.x; ay += wB * h1.y;
      ax += wC * h2.x; ay += wC * h2.y;
      ax += wD * h3.x; ay += wD * h3.y;
      ax += wE * h4.x; ay += wE * h4.y;
      ax += wF * h5.x; ay += wF * h5.y;
      ax += wG * h6.x; ay += wG * h6.y;
      ax += wH * h7.x; ay += wH * h7.y;
    }
    for (; jj + 4 <= deg; jj += 4) {
      int i0 = sv_lds[wl][jj + 0], i1 = sv_lds[wl][jj + 1];
      int i2 = sv_lds[wl][jj + 2], i3 = sv_lds[wl][jj + 3];
      float wA = w_lds[wl][jj + 0][head], wB = w_lds[wl][jj + 1][head];
      float wC = w_lds[wl][jj + 2][head], wD = w_lds[wl][jj + 3][head];
      float2 h0 = __half22float2(*(const __half2*)(h + (size_t)i0 * HC + lane * 2));
      float2 h1 = __half22float2(*(const __half2*)(h + (size_t)i1 * HC + lane * 2));
      float2 h2 = __half22float2(*(const __half2*)(h + (size_t)i2 * HC + lane * 2));
      float2 h3 = __half22float2(*(const __half2*)(h + (size_t)i3 * HC + lane * 2));
      ax += wA * h0.x; ay += wA * h0.y;
      ax += wB * h1.x; ay += wB * h1.y;
      ax += wC * h2.x; ay += wC * h2.y;
      ax += wD * h3.x; ay += wD * h3.y;
    }
    for (; jj < deg; jj++) {
      int i0 = sv_lds[wl][jj];
      float wA = w_lds[wl][jj][head];
      float2 h0 = __half22float2(*(const __half2*)(h + (size_t)i0 * HC + lane * 2));
      ax += wA * h0.x; ay += wA * h0.y;
    }
  } else {
    // rare generic path (deg > 64): chunked two-pass
    float M0 = -1e30f, M1 = -1e30f, M2 = -1e30f, M3 = -1e30f;
    for (int c = lo; c < hi; c += 64) {
      int j = c + lane;
      int sv = (j < hi) ? csr_src[j] : 0;
      float4 a4 = ((const float4*)asrc)[sv];
      bool valid = (j < hi);
      float e0 = valid ? lrelu(a4.x + ad4.x) : -1e30f;
      float e1 = valid ? lrelu(a4.y + ad4.y) : -1e30f;
      float e2 = valid ? lrelu(a4.z + ad4.z) : -1e30f;
      float e3 = valid ? lrelu(a4.w + ad4.w) : -1e30f;
      BFLY_MAX4(e0, e1, e2, e3)
      M0 = fmaxf(M0, e0); M1 = fmaxf(M1, e1);
      M2 = fmaxf(M2, e2); M3 = fmaxf(M3, e3);
    }
    float S0 = 0.f, S1 = 0.f, S2 = 0.f, S3 = 0.f;
    for (int c = lo; c < hi; c += 64) {
      int j = c + lane;
      int sv = (j < hi) ? csr_src[j] : 0;
      float4 a4 = ((const float4*)asrc)[sv];
      bool valid = (j < hi);
      float e0 = valid ? lrelu(a4.x + ad4.x) : -1e30f;
      float e1 = valid ? lrelu(a4.y + ad4.y) : -1e30f;
      float e2 = valid ? lrelu(a4.z + ad4.z) : -1e30f;
      float e3 = valid ? lrelu(a4.w + ad4.w) : -1e30f;
      float w0 = expf(e0 - M0), w1 = expf(e1 - M1);
      float w2 = expf(e2 - M2), w3 = expf(e3 - M3);
      float s0 = w0, s1 = w1, s2 = w2, s3 = w3;
      BFLY_SUM4(s0, s1, s2, s3)
      S0 += s0; S1 += s1; S2 += s2; S3 += s3;
      sv_lds[wl][lane] = sv;
      *(float4*)&w_lds[wl][lane][0] = make_float4(w0, w1, w2, w3);
      int cnt = (hi - c < 64) ? (hi - c) : 64;
      int jj = 0;
      for (; jj + 4 <= cnt; jj += 4) {
        int i0 = sv_lds[wl][jj + 0], i1 = sv_lds[wl][jj + 1];
        int i2 = sv_lds[wl][jj + 2], i3 = sv_lds[wl][jj + 3];
        float wA = w_lds[wl][jj + 0][head], wB = w_lds[wl][jj + 1][head];
        float wC = w_lds[wl][jj + 2][head], wD = w_lds[wl][jj + 3][head];
        float2 h0 = __half22float2(*(const __half2*)(h + (size_t)i0 * HC + lane * 2));
        float2 h1 = __half22float2(*(const __half2*)(h + (size_t)i1 * HC + lane * 2));
        float2 h2 = __half22float2(*(const __half2*)(h + (size_t)i2 * HC + lane * 2));
        float2 h3 = __half22float2(*(const __half2*)(h + (size_t)i3 * HC + lane * 2));
        ax += wA * h0.x; ay += wA * h0.y;
        ax += wB * h1.x; ay += wB * h1.y;
        ax += wC * h2.x; ay += wC * h2.y;
        ax += wD * h3.x; ay += wD * h3.y;
      }
      for (; jj < cnt; jj++) {
        int i0 = sv_lds[wl][jj];
        float wA = w_lds[wl][jj][head];
        float2 h0 = __half22float2(*(const __half2*)(h + (size_t)i0 * HC + lane * 2));
        ax += wA * h0.x; ay += wA * h0.y;
      }
    }
    S = (head == 0) ? S0 : (head == 1) ? S1 : (head == 2) ? S2 : S3;
  }

  float rden = 1.f / S;
  float2 b = *(const float2*)(bias + lane * 2);
  float vx = fmaxf(ax * rden + b.x, 0.f);
  float vy = fmaxf(ay * rden + b.y, 0.f);
  *(float2*)(out_h + (size_t)node * HC + lane * 2) = make_float2(vx, vy);
  if (do_pool) {
    int g = batch[node];
    unsigned* pp = pooled + g * HC + lane * 2;
    // post-relu values >= 0: bit compare == float compare; init 0 matches the
    // reference's where(isfinite, pooled, 0) empty-graph guard.
    atomicMax(pp + 0, __float_as_uint(vx));
    atomicMax(pp + 1, __float_as_uint(vy));
  }
}

// final head: out[g] = (pooled[g] @ Wlin + blin) @ Wout + bout ; 1 block/graph
__global__ __launch_bounds__(256) void k_mlp(
    const float* __restrict__ pooled, const float* __restrict__ Wlin,
    const float* __restrict__ blin, const float* __restrict__ Wout,
    const float* __restrict__ bout, float* __restrict__ out) {
  __shared__ float p[HC];
  __shared__ float z[LIN];
  int g = blockIdx.x, tid = threadIdx.x;
  if (tid < HC) p[tid] = pooled[g * HC + tid];
  __syncthreads();
  float zv = blin[tid];
  for (int k = 0; k < HC; k++) zv += p[k] * Wlin[k * LIN + tid];
  z[tid] = zv;
  __syncthreads();
  if (tid < OUTC) {
    float o = bout[tid];
    for (int k = 0; k < LIN; k++) o += z[k] * Wout[k * OUTC + tid];
    out[g * OUTC + tid] = o;
  }
}

extern "C" void kernel_launch(void* const* d_in, const int* in_sizes, int n_in,
                              void* d_out, int out_size, void* d_ws, size_t ws_size,
                              hipStream_t stream) {
  const float* x     = (const float*)d_in[0];
  const int*   ei    = (const int*)d_in[1];
  const int*   batch = (const int*)d_in[2];
  const float* Wl[3] = {(const float*)d_in[3], (const float*)d_in[7], (const float*)d_in[11]};
  const float* As[3] = {(const float*)d_in[4], (const float*)d_in[8], (const float*)d_in[12]};
  const float* Ad[3] = {(const float*)d_in[5], (const float*)d_in[9], (const float*)d_in[13]};
  const float* Bi[3] = {(const float*)d_in[6], (const float*)d_in[10], (const float*)d_in[14]};
  const float* Wlin  = (const float*)d_in[15];
  const float* blin  = (const float*)d_in[16];
  const float* Wout  = (const float*)d_in[17];
  const float* bout  = (const float*)d_in[18];
  float* out = (float*)d_out;

  // workspace layout (float offsets); h is fp16 (N*128 halves = 3.2M floats)
  float* ws = (float*)d_ws;
  __half*   h       = (__half*)ws;                 // N*128 halves
  float*    nodeB   = ws + 6400000;                // N*128 fp32
  float*    asrc    = ws + 12800000;               // N*4
  float*    adst    = ws + 13000000;               // N*4
  int*      deg     = (int*)(ws + 13200000);       // N
  int*      cnt     = (int*)(ws + 13250000);       // N (adjacent to deg)
  int*      row_off = (int*)(ws + 13300000);       // N+1
  int*      csr_src = (int*)(ws + 13350008);       // E_TOT
  unsigned* pooled  = (unsigned*)(ws + 14200008);  // 64*128

  const int* srcp = ei;
  const int* dstp = ei + E_EDGES;

  hipMemsetAsync(deg, 0, 2 * N_NODES * sizeof(int), stream);

  // CSR by dst — built once, reused by all 3 layers
  k_hist<<<(E_TOT + 255) / 256, 256, 0, stream>>>(dstp, deg);
  k_scan<<<1, 1024, 0, stream>>>(deg, row_off, pooled);
  k_scatter<<<(E_TOT + 255) / 256, 256, 0, stream>>>(srcp, dstp, row_off, cnt, csr_src);

  const float* lin_in = x;
  for (int L = 0; L < 3; L++) {
    k_gemm_alpha<<<(N_NODES + 127) / 128, 256, 0, stream>>>(
        lin_in, Wl[L], As[L], Ad[L], h, asrc, adst);
    k_aggr<<<(N_NODES * 64 + 255) / 256, 256, 0, stream>>>(
        row_off, csr_src, asrc, adst, h, Bi[L], batch,
        nodeB, pooled, (L == 2) ? 1 : 0);
    lin_in = nodeB;
  }
  k_mlp<<<NG, 256, 0, stream>>>((const float*)pooled, Wlin, blin, Wout, bout, out);
}

// Round 12
// 551.306 us; speedup vs baseline: 1.4732x; 1.1206x over previous
//
#include <hip/hip_runtime.h>
#include <hip/hip_fp16.h>
#include <math.h>

#define N_NODES 50000
#define E_EDGES 800000
#define E_TOT   850000   // E + N self loops
#define HC 128
#define NHEAD 4
#define LIN 256
#define OUTC 10
#define NG 64
#define NEG_SLOPE 0.2f

__device__ __forceinline__ float lrelu(float v) { return v > 0.f ? v : NEG_SLOPE * v; }

typedef _Float16 half8v __attribute__((ext_vector_type(8)));
typedef float    float4v __attribute__((ext_vector_type(4)));

// ---------------------------------------------------------------------------
// MFMA GEMM + attention logits. h = x@W via v_mfma_f32_16x16x32_f16
// (fp16 inputs, fp32 accumulate). Block = 256 thr = 4 waves; wave = 16 rows.
// W is transposed+converted to fp16 in LDS (padded stride 136 halves so
// B-frag ds_read_b128 is ~conflict-free). Fragment layouts (verified m89/m120):
//   A: lane(m=lane&15, quad=lane>>4) holds A[m][quad*8+j], j=0..7
//   B: lane(n=lane&15, quad)        holds B[quad*8+j][n]
//   C/D: col=lane&15, row=quad*4+reg
// Epilogue: C -> LDS fp16 stage -> coalesced dwordx4 h store; alpha dot from
// the staged tile. h emitted fp16 (only consumer is the gather).
// ---------------------------------------------------------------------------
__global__ __launch_bounds__(256) void k_gemm_mfma(
    const float* __restrict__ x, const float* __restrict__ W,
    const float* __restrict__ a_s, const float* __restrict__ a_d,
    __half* __restrict__ h, float* __restrict__ asrc, float* __restrict__ adst) {
  __shared__ _Float16 Wt[128 * 136];       // W^T fp16, padded row stride 136
  __shared__ _Float16 hst[4][16][136];     // per-wave C staging (padded)
  __shared__ float aS[HC], aD[HC];
  int tid = threadIdx.x;
  if (tid < HC) { aS[tid] = a_s[tid]; aD[tid] = a_d[tid]; }
  // transpose + convert W (coalesced global read, scattered one-time LDS write)
  for (int i = 0; i < 64; i++) {
    int idx = tid + i * 256;               // 16384 elements
    int k = idx >> 7, n = idx & 127;
    Wt[n * 136 + k] = (_Float16)W[idx];
  }
  __syncthreads();

  int wv = tid >> 6, lane = tid & 63;
  int quad = lane >> 4, low = lane & 15;
  int rowbase = blockIdx.x * 64 + wv * 16;
  int row = rowbase + low;
  int rowc = row < N_NODES ? row : N_NODES - 1;  // clamp; stores guarded

  float4v acc[8];
#pragma unroll
  for (int t = 0; t < 8; t++) acc[t] = (float4v){0.f, 0.f, 0.f, 0.f};

#pragma unroll
  for (int k4 = 0; k4 < 4; k4++) {
    int kb = k4 * 32 + quad * 8;
    float4 xa = *(const float4*)(x + (size_t)rowc * HC + kb);
    float4 xb = *(const float4*)(x + (size_t)rowc * HC + kb + 4);
    half8v af;
    af[0] = (_Float16)xa.x; af[1] = (_Float16)xa.y;
    af[2] = (_Float16)xa.z; af[3] = (_Float16)xa.w;
    af[4] = (_Float16)xb.x; af[5] = (_Float16)xb.y;
    af[6] = (_Float16)xb.z; af[7] = (_Float16)xb.w;
    half8v bf[8];
#pragma unroll
    for (int t = 0; t < 8; t++)
      bf[t] = *(const half8v*)&Wt[(t * 16 + low) * 136 + kb];
#pragma unroll
    for (int t = 0; t < 8; t++)
      acc[t] = __builtin_amdgcn_mfma_f32_16x16x32_f16(af, bf[t], acc[t], 0, 0, 0);
  }

  // stage C (fp16) into LDS: lane writes rows quad*4+r, feature t*16+low
#pragma unroll
  for (int t = 0; t < 8; t++)
#pragma unroll
    for (int r = 0; r < 4; r++)
      hst[wv][quad * 4 + r][t * 16 + low] = (_Float16)acc[t][r];
  __syncthreads();

  // coalesced h store: lane -> row lane/4, 64B quarter lane%4
  {
    int r = lane >> 2, part = lane & 3;
    int grow = rowbase + r;
    if (grow < N_NODES) {
      const float4* src = (const float4*)&hst[wv][r][part * 32];
      float4* dst = (float4*)(h + (size_t)grow * HC + part * 32);
#pragma unroll
      for (int i = 0; i < 4; i++) dst[i] = src[i];
    }
  }
  // alpha: lane (row=low, head=quad) dots 32 staged feats with a_s / a_d
  {
    int grow = rowbase + low;
    float ss = 0.f, dd = 0.f;
#pragma unroll
    for (int i = 0; i < 32; i++) {
      float hv = (float)hst[wv][low][quad * 32 + i];
      ss += hv * aS[quad * 32 + i];
      dd += hv * aD[quad * 32 + i];
    }
    if (grow < N_NODES) {
      asrc[grow * NHEAD + quad] = ss;
      adst[grow * NHEAD + quad] = dd;
    }
  }
}

// ---------------------------------------------------------------------------
// CSR build: histogram -> exclusive scan -> scatter (int atomics only)
// ---------------------------------------------------------------------------
__global__ __launch_bounds__(256) void k_hist(
    const int* __restrict__ dst, int* __restrict__ deg) {
  int e = blockIdx.x * 256 + threadIdx.x;
  if (e >= E_TOT) return;
  int d = (e < E_EDGES) ? dst[e] : e - E_EDGES;
  atomicAdd(&deg[d], 1);
}

__global__ __launch_bounds__(1024) void k_scan(
    const int* __restrict__ deg, int* __restrict__ row_off,
    unsigned* __restrict__ pooled) {
  // fold the pooled zeroing in here (saves one dispatch)
  if (threadIdx.x < NG * HC / 8) {
    ((uint2*)pooled)[threadIdx.x * 4 + 0] = make_uint2(0u, 0u);
    ((uint2*)pooled)[threadIdx.x * 4 + 1] = make_uint2(0u, 0u);
    ((uint2*)pooled)[threadIdx.x * 4 + 2] = make_uint2(0u, 0u);
    ((uint2*)pooled)[threadIdx.x * 4 + 3] = make_uint2(0u, 0u);
  }
  __shared__ int ps[1024];
  int tid = threadIdx.x;
  const int CH = (N_NODES + 1023) / 1024;  // 49
  int base = tid * CH;
  int sum = 0;
  for (int i = 0; i < CH; i++) {
    int idx = base + i;
    if (idx < N_NODES) sum += deg[idx];
  }
  ps[tid] = sum;
  __syncthreads();
  for (int off = 1; off < 1024; off <<= 1) {
    int v = (tid >= off) ? ps[tid - off] : 0;
    __syncthreads();
    ps[tid] += v;
    __syncthreads();
  }
  int run = (tid ? ps[tid - 1] : 0);
  for (int i = 0; i < CH; i++) {
    int idx = base + i;
    if (idx < N_NODES) { row_off[idx] = run; run += deg[idx]; }
  }
  if (tid == 1023) row_off[N_NODES] = run;
}

__global__ __launch_bounds__(256) void k_scatter(
    const int* __restrict__ src, const int* __restrict__ dst,
    const int* __restrict__ row_off, int* __restrict__ cnt,
    int* __restrict__ csr_src) {
  int e = blockIdx.x * 256 + threadIdx.x;
  if (e >= E_TOT) return;
  int s, d;
  if (e < E_EDGES) { s = src[e]; d = dst[e]; } else { s = d = e - E_EDGES; }
  int pos = row_off[d] + atomicAdd(&cnt[d], 1);
  csr_src[pos] = s;
}

#define BFLY_MAX4(m0, m1, m2, m3)                         \
  _Pragma("unroll") for (int off = 1; off < 64; off <<= 1) { \
    m0 = fmaxf(m0, __shfl_xor(m0, off));                  \
    m1 = fmaxf(m1, __shfl_xor(m1, off));                  \
    m2 = fmaxf(m2, __shfl_xor(m2, off));                  \
    m3 = fmaxf(m3, __shfl_xor(m3, off));                  \
  }
#define BFLY_SUM4(s0, s1, s2, s3)                         \
  _Pragma("unroll") for (int off = 1; off < 64; off <<= 1) { \
    s0 += __shfl_xor(s0, off);                            \
    s1 += __shfl_xor(s1, off);                            \
    s2 += __shfl_xor(s2, off);                            \
    s3 += __shfl_xor(s3, off);                            \
  }

// ---------------------------------------------------------------------------
// Fused softmax + aggregation — R6 structure with fp16 h (best measured:
// 143 us). One wave per dst node; lane owns 2 feats; head = lane/16.
// LAW (R5/R7/R10): every gather instruction's 64 lanes must cover exactly ONE
// contiguous h-row span — never split the wave's lanes across rows.
// ---------------------------------------------------------------------------
__global__ __launch_bounds__(256) void k_aggr(
    const int* __restrict__ row_off, const int* __restrict__ csr_src,
    const float* __restrict__ asrc, const float* __restrict__ adst,
    const __half* __restrict__ h, const float* __restrict__ bias,
    const int* __restrict__ batch, float* __restrict__ out_h,
    unsigned* __restrict__ pooled, int do_pool) {
  __shared__ int   sv_lds[4][64];
  __shared__ float w_lds[4][64][4];
  int gid = blockIdx.x * 256 + threadIdx.x;
  int node = gid >> 6, lane = gid & 63, wl = threadIdx.x >> 6;
  if (node >= N_NODES) return;
  int head = lane >> 4;
  int lo = row_off[node], hi = row_off[node + 1];
  int deg = hi - lo;
  float4 ad4 = ((const float4*)adst)[node];  // broadcast
  float ax = 0.f, ay = 0.f;
  float S;

  if (deg <= 64) {
    int j = lo + lane;
    int sv = (j < hi) ? csr_src[j] : 0;
    float4 a4 = ((const float4*)asrc)[sv];
    bool valid = (j < hi);
    float e0 = valid ? lrelu(a4.x + ad4.x) : -1e30f;
    float e1 = valid ? lrelu(a4.y + ad4.y) : -1e30f;
    float e2 = valid ? lrelu(a4.z + ad4.z) : -1e30f;
    float e3 = valid ? lrelu(a4.w + ad4.w) : -1e30f;
    float m0 = e0, m1 = e1, m2 = e2, m3 = e3;
    BFLY_MAX4(m0, m1, m2, m3)
    float w0 = expf(e0 - m0), w1 = expf(e1 - m1);
    float w2 = expf(e2 - m2), w3 = expf(e3 - m3);  // invalid lanes -> 0
    float s0 = w0, s1 = w1, s2 = w2, s3 = w3;
    BFLY_SUM4(s0, s1, s2, s3)
    sv_lds[wl][lane] = sv;
    *(float4*)&w_lds[wl][lane][0] = make_float4(w0, w1, w2, w3);
    S = (head == 0) ? s0 : (head == 1) ? s1 : (head == 2) ? s2 : s3;
    int jj = 0;
    for (; jj + 8 <= deg; jj += 8) {
      int i0 = sv_lds[wl][jj + 0], i1 = sv_lds[wl][jj + 1];
      int i2 = sv_lds[wl][jj + 2], i3 = sv_lds[wl][jj + 3];
      int i4 = sv_lds[wl][jj + 4], i5 = sv_lds[wl][jj + 5];
      int i6 = sv_lds[wl][jj + 6], i7 = sv_lds[wl][jj + 7];
      float wA = w_lds[wl][jj + 0][head], wB = w_lds[wl][jj + 1][head];
      float wC = w_lds[wl][jj + 2][head], wD = w_lds[wl][jj + 3][head];
      float wE = w_lds[wl][jj + 4][head], wF = w_lds[wl][jj + 5][head];
      float wG = w_lds[wl][jj + 6][head], wH = w_lds[wl][jj + 7][head];
      float2 h0 = __half22float2(*(const __half2*)(h + (size_t)i0 * HC + lane * 2));
      float2 h1 = __half22float2(*(const __half2*)(h + (size_t)i1 * HC + lane * 2));
      float2 h2 = __half22float2(*(const __half2*)(h + (size_t)i2 * HC + lane * 2));
      float2 h3 = __half22float2(*(const __half2*)(h + (size_t)i3 * HC + lane * 2));
      float2 h4 = __half22float2(*(const __half2*)(h + (size_t)i4 * HC + lane * 2));
      float2 h5 = __half22float2(*(const __half2*)(h + (size_t)i5 * HC + lane * 2));
      float2 h6 = __half22float2(*(const __half2*)(h + (size_t)i6 * HC + lane * 2));
      float2 h7 = __half22float2(*(const __half2*)(h + (size_t)i7 * HC + lane * 2));
      ax += wA * h0.x; ay += wA * h0.y;
      ax += wB * h1.x; ay += wB * h1.y;
      ax += wC * h2.x; ay += wC * h2.y;
      ax += wD * h3.x; ay += wD * h3.y;
      ax += wE * h4.x; ay += wE * h4.y;
      ax += wF * h5.x; ay += wF * h5.y;
      ax += wG * h6.x; ay += wG * h6.y;
      ax += wH * h7.x; ay += wH * h7.y;
    }
    for (; jj + 4 <= deg; jj += 4) {
      int i0 = sv_lds[wl][jj + 0], i1 = sv_lds[wl][jj + 1];
      int i2 = sv_lds[wl][jj + 2], i3 = sv_lds[wl][jj + 3];
      float wA = w_lds[wl][jj + 0][head], wB = w_lds[wl][jj + 1][head];
      float wC = w_lds[wl][jj + 2][head], wD = w_lds[wl][jj + 3][head];
      float2 h0 = __half22float2(*(const __half2*)(h + (size_t)i0 * HC + lane * 2));
      float2 h1 = __half22float2(*(const __half2*)(h + (size_t)i1 * HC + lane * 2));
      float2 h2 = __half22float2(*(const __half2*)(h + (size_t)i2 * HC + lane * 2));
      float2 h3 = __half22float2(*(const __half2*)(h + (size_t)i3 * HC + lane * 2));
      ax += wA * h0.x; ay += wA * h0.y;
      ax += wB * h1.x; ay += wB * h1.y;
      ax += wC * h2.x; ay += wC * h2.y;
      ax += wD * h3.x; ay += wD * h3.y;
    }
    for (; jj < deg; jj++) {
      int i0 = sv_lds[wl][jj];
      float wA = w_lds[wl][jj][head];
      float2 h0 = __half22float2(*(const __half2*)(h + (size_t)i0 * HC + lane * 2));
      ax += wA * h0.x; ay += wA * h0.y;
    }
  } else {
    // rare generic path (deg > 64): chunked two-pass
    float M0 = -1e30f, M1 = -1e30f, M2 = -1e30f, M3 = -1e30f;
    for (int c = lo; c < hi; c += 64) {
      int j = c + lane;
      int sv = (j < hi) ? csr_src[j] : 0;
      float4 a4 = ((const float4*)asrc)[sv];
      bool valid = (j < hi);
      float e0 = valid ? lrelu(a4.x + ad4.x) : -1e30f;
      float e1 = valid ? lrelu(a4.y + ad4.y) : -1e30f;
      float e2 = valid ? lrelu(a4.z + ad4.z) : -1e30f;
      float e3 = valid ? lrelu(a4.w + ad4.w) : -1e30f;
      BFLY_MAX4(e0, e1, e2, e3)
      M0 = fmaxf(M0, e0); M1 = fmaxf(M1, e1);
      M2 = fmaxf(M2, e2); M3 = fmaxf(M3, e3);
    }
    float S0 = 0.f, S1 = 0.f, S2 = 0.f, S3 = 0.f;
    for (int c = lo; c < hi; c += 64) {
      int j = c + lane;
      int sv = (j < hi) ? csr_src[j] : 0;
      float4 a4 = ((const float4*)asrc)[sv];
      bool valid = (j < hi);
      float e0 = valid ? lrelu(a4.x + ad4.x) : -1e30f;
      float e1 = valid ? lrelu(a4.y + ad4.y) : -1e30f;
      float e2 = valid ? lrelu(a4.z + ad4.z) : -1e30f;
      float e3 = valid ? lrelu(a4.w + ad4.w) : -1e30f;
      float w0 = expf(e0 - M0), w1 = expf(e1 - M1);
      float w2 = expf(e2 - M2), w3 = expf(e3 - M3);
      float s0 = w0, s1 = w1, s2 = w2, s3 = w3;
      BFLY_SUM4(s0, s1, s2, s3)
      S0 += s0; S1 += s1; S2 += s2; S3 += s3;
      sv_lds[wl][lane] = sv;
      *(float4*)&w_lds[wl][lane][0] = make_float4(w0, w1, w2, w3);
      int cnt = (hi - c < 64) ? (hi - c) : 64;
      int jj = 0;
      for (; jj + 4 <= cnt; jj += 4) {
        int i0 = sv_lds[wl][jj + 0], i1 = sv_lds[wl][jj + 1];
        int i2 = sv_lds[wl][jj + 2], i3 = sv_lds[wl][jj + 3];
        float wA = w_lds[wl][jj + 0][head], wB = w_lds[wl][jj + 1][head];
        float wC = w_lds[wl][jj + 2][head], wD = w_lds[wl][jj + 3][head];
        float2 h0 = __half22float2(*(const __half2*)(h + (size_t)i0 * HC + lane * 2));
        float2 h1 = __half22float2(*(const __half2*)(h + (size_t)i1 * HC + lane * 2));
        float2 h2 = __half22float2(*(const __half2*)(h + (size_t)i2 * HC + lane * 2));
        float2 h3 = __half22float2(*(const __half2*)(h + (size_t)i3 * HC + lane * 2));
        ax += wA * h0.x; ay += wA * h0.y;
        ax += wB * h1.x; ay += wB * h1.y;
        ax += wC * h2.x; ay += wC * h2.y;
        ax += wD * h3.x; ay += wD * h3.y;
      }
      for (; jj < cnt; jj++) {
        int i0 = sv_lds[wl][jj];
        float wA = w_lds[wl][jj][head];
        float2 h0 = __half22float2(*(const __half2*)(h + (size_t)i0 * HC + lane * 2));
        ax += wA * h0.x; ay += wA * h0.y;
      }
    }
    S = (head == 0) ? S0 : (head == 1) ? S1 : (head == 2) ? S2 : S3;
  }

  float rden = 1.f / S;
  float2 b = *(const float2*)(bias + lane * 2);
  float vx = fmaxf(ax * rden + b.x, 0.f);
  float vy = fmaxf(ay * rden + b.y, 0.f);
  *(float2*)(out_h + (size_t)node * HC + lane * 2) = make_float2(vx, vy);
  if (do_pool) {
    int g = batch[node];
    unsigned* pp = pooled + g * HC + lane * 2;
    // post-relu values >= 0: bit compare == float compare; init 0 matches the
    // reference's where(isfinite, pooled, 0) empty-graph guard.
    atomicMax(pp + 0, __float_as_uint(vx));
    atomicMax(pp + 1, __float_as_uint(vy));
  }
}

// final head: out[g] = (pooled[g] @ Wlin + blin) @ Wout + bout ; 1 block/graph
__global__ __launch_bounds__(256) void k_mlp(
    const float* __restrict__ pooled, const float* __restrict__ Wlin,
    const float* __restrict__ blin, const float* __restrict__ Wout,
    const float* __restrict__ bout, float* __restrict__ out) {
  __shared__ float p[HC];
  __shared__ float z[LIN];
  int g = blockIdx.x, tid = threadIdx.x;
  if (tid < HC) p[tid] = pooled[g * HC + tid];
  __syncthreads();
  float zv = blin[tid];
  for (int k = 0; k < HC; k++) zv += p[k] * Wlin[k * LIN + tid];
  z[tid] = zv;
  __syncthreads();
  if (tid < OUTC) {
    float o = bout[tid];
    for (int k = 0; k < LIN; k++) o += z[k] * Wout[k * OUTC + tid];
    out[g * OUTC + tid] = o;
  }
}

extern "C" void kernel_launch(void* const* d_in, const int* in_sizes, int n_in,
                              void* d_out, int out_size, void* d_ws, size_t ws_size,
                              hipStream_t stream) {
  const float* x     = (const float*)d_in[0];
  const int*   ei    = (const int*)d_in[1];
  const int*   batch = (const int*)d_in[2];
  const float* Wl[3] = {(const float*)d_in[3], (const float*)d_in[7], (const float*)d_in[11]};
  const float* As[3] = {(const float*)d_in[4], (const float*)d_in[8], (const float*)d_in[12]};
  const float* Ad[3] = {(const float*)d_in[5], (const float*)d_in[9], (const float*)d_in[13]};
  const float* Bi[3] = {(const float*)d_in[6], (const float*)d_in[10], (const float*)d_in[14]};
  const float* Wlin  = (const float*)d_in[15];
  const float* blin  = (const float*)d_in[16];
  const float* Wout  = (const float*)d_in[17];
  const float* bout  = (const float*)d_in[18];
  float* out = (float*)d_out;

  // workspace layout (float offsets); h is fp16 (N*128 halves = 3.2M floats)
  float* ws = (float*)d_ws;
  __half*   h       = (__half*)ws;                 // N*128 halves
  float*    nodeB   = ws + 6400000;                // N*128 fp32
  float*    asrc    = ws + 12800000;               // N*4
  float*    adst    = ws + 13000000;               // N*4
  int*      deg     = (int*)(ws + 13200000);       // N
  int*      cnt     = (int*)(ws + 13250000);       // N (adjacent to deg)
  int*      row_off = (int*)(ws + 13300000);       // N+1
  int*      csr_src = (int*)(ws + 13350008);       // E_TOT
  unsigned* pooled  = (unsigned*)(ws + 14200008);  // 64*128

  const int* srcp = ei;
  const int* dstp = ei + E_EDGES;

  hipMemsetAsync(deg, 0, 2 * N_NODES * sizeof(int), stream);

  // CSR by dst — built once, reused by all 3 layers
  k_hist<<<(E_TOT + 255) / 256, 256, 0, stream>>>(dstp, deg);
  k_scan<<<1, 1024, 0, stream>>>(deg, row_off, pooled);
  k_scatter<<<(E_TOT + 255) / 256, 256, 0, stream>>>(srcp, dstp, row_off, cnt, csr_src);

  const float* lin_in = x;
  for (int L = 0; L < 3; L++) {
    k_gemm_mfma<<<(N_NODES + 63) / 64, 256, 0, stream>>>(
        lin_in, Wl[L], As[L], Ad[L], h, asrc, adst);
    k_aggr<<<(N_NODES * 64 + 255) / 256, 256, 0, stream>>>(
        row_off, csr_src, asrc, adst, h, Bi[L], batch,
        nodeB, pooled, (L == 2) ? 1 : 0);
    lin_in = nodeB;
  }
  k_mlp<<<NG, 256, 0, stream>>>((const float*)pooled, Wlin, blin, Wout, bout, out);
}